// Round 7
// baseline (369.194 us; speedup 1.0000x reference)
//
#include <hip/hip_runtime.h>
#include <math.h>

#define S 256
#define NB 4
#define TAU 0.1f
#define KSEL 128
#define LOG_TAB 21
#define TAB_SZ (1u << LOG_TAB)
#define TAB_MASK (TAB_SZ - 1)
#define EMPTY64 0xFFFFFFFFFFFFFFFFull
#define BM_WORDS (1u << 21)   // 4*256^3 bits / 32
#define NBINS 8192
#define BIN_BASE 0x3D800      // (0x3D800000 >> 12), conf floor 0.0625 < TAU
#define CAND_CAP 4096
#define CPAD 32               // ints per counter slot -> one 128B line each

typedef unsigned long long u64;
typedef unsigned int u32;

__device__ __forceinline__ u32 hash_key(int key) {
    u32 h = (u32)key * 0x9E3779B1u;
    h ^= h >> 15;
    return h & TAB_MASK;
}

__device__ __forceinline__ int conf_bin(float conf) {
    int bin = (int)(__float_as_uint(conf) >> 12) - BIN_BASE;
    return bin < 0 ? 0 : (bin > NBINS - 1 ? NBINS - 1 : bin);
}

__global__ void k_init(u64* __restrict__ tab, u32* __restrict__ bm, int* __restrict__ cnt,
                       int* __restrict__ hist, int* __restrict__ ccnt, u32* __restrict__ thrbin) {
    int i = blockIdx.x * blockDim.x + threadIdx.x;
    if (i < (int)TAB_SZ) tab[i] = EMPTY64;
    if (i < (int)BM_WORDS) bm[i] = 0u;
    if (i < NB * NBINS) hist[i] = 0;
    if (i < NB * CPAD) { cnt[i] = 0; ccnt[i] = 0; }
    if (i < NB) thrbin[i] = 0;
}

// Insert (key -> min index) AND set bm bit with own conf. bm = OR over dups with
// conf>TAU: superset of "rep conf>TAU"; false positives only ever add cj<=TAU<conf
// to hmax, which cannot change the (hmax==conf) peak decision.
__global__ void k_insert(const int* __restrict__ coords, const float* __restrict__ scores,
                         u64* __restrict__ tab, u32* __restrict__ bm, int N) {
    int i = blockIdx.x * blockDim.x + threadIdx.x;
    if (i >= N) return;
    int4 c = ((const int4*)coords)[i];
    float conf = scores[i];
    int key = ((c.x * S + c.y) * S + c.z) * S + c.w;
    if (conf > TAU) atomicOr(&bm[(u32)key >> 5], 1u << (key & 31));
    u64 ins = ((u64)(u32)key << 32) | (u32)i;
    u32 slot = hash_key(key);
    for (;;) {
        u64 e = tab[slot];
        if ((u32)(e >> 32) == (u32)key) { atomicMin(&tab[slot], ins); return; }
        if (e == EMPTY64) {
            u64 prev = atomicCAS(&tab[slot], EMPTY64, ins);
            if (prev == EMPTY64) return;
            if ((u32)(prev >> 32) == (u32)key) { atomicMin(&tab[slot], ins); return; }
        }
        slot = (slot + 1) & TAB_MASK;
    }
}

__device__ __forceinline__ int tab_lookup(const u64* __restrict__ tab, int key) {
    u32 slot = hash_key(key);
    for (;;) {
        u64 e = tab[slot];
        if ((u32)(e >> 32) == (u32)key) return (int)(u32)e;
        if (e == EMPTY64) return -1;
        slot = (slot + 1) & TAB_MASK;
    }
}

// Peak detect (z-packed bitmask + sparse probes) + hist + block-aggregated compaction.
__global__ void k_peak(const int* __restrict__ coords, const float* __restrict__ scores,
                       const u64* __restrict__ tab, const u32* __restrict__ bm,
                       u64* __restrict__ peaks, int* __restrict__ cnt, int* __restrict__ hist,
                       int N, int pcap) {
    int i = blockIdx.x * blockDim.x + threadIdx.x;
    bool alive = (i < N);
    int ii = alive ? i : 0;
    int4 c = ((const int4*)coords)[ii];
    float conf = alive ? scores[ii] : -1.0f;
    int kb = ((c.x * S + c.y) * S + c.z) * S + c.w;
    bool ispeak = false;
    if (alive && conf > TAU) {
        u32 m27 = 0;
        u32 vzm = (u32)((c.w > 0) ? 1 : 0) | 2u | (u32)((c.w < S - 1) ? 4 : 0);
        #pragma unroll
        for (int dx = -1; dx <= 1; dx++) {
            if ((unsigned)(c.y + dx) >= S) continue;
            #pragma unroll
            for (int dy = -1; dy <= 1; dy++) {
                if ((unsigned)(c.z + dy) >= S) continue;
                int nk = kb + dx * (S * S) + dy * S;   // center-z key of this column
                u32 idx = (u32)nk >> 5;
                int sft = nk & 31;
                u32 w0 = bm[idx];
                u32 b3;
                if (sft >= 1 && sft <= 30) {
                    b3 = (w0 >> (sft - 1)) & 7u;
                } else if (sft == 0) {
                    u32 wm = (nk >= 32) ? bm[idx - 1] : 0u;
                    b3 = ((wm >> 31) & 1u) | ((w0 & 3u) << 1);
                } else { // sft == 31
                    u32 wp = (idx + 1 < BM_WORDS) ? bm[idx + 1] : 0u;
                    b3 = ((w0 >> 30) & 3u) | ((wp & 1u) << 2);
                }
                b3 &= vzm;
                int p = ((dx + 1) * 3 + (dy + 1)) * 3;
                m27 |= b3 << p;
            }
        }
        float hmax = -INFINITY;
        while (m27) {
            int q = __builtin_ctz(m27);
            m27 &= m27 - 1;
            int dx = q / 9 - 1;
            int r = q % 9;
            int dy = r / 3 - 1, dz = r % 3 - 1;
            int j = tab_lookup(tab, kb + dx * (S * S) + dy * S + dz);
            if (j >= 0) hmax = fmaxf(hmax, scores[j]); // cj<=TAU contributions harmless
        }
        ispeak = (hmax == conf);
    }

    if (ispeak) atomicAdd(&hist[c.x * NBINS + conf_bin(conf)], 1);

    // block-aggregated compaction: 4 padded atomics per BLOCK
    __shared__ int wcnt[4][NB];
    __shared__ int bbase[NB];
    int w = threadIdx.x >> 6;
    int lane = threadIdx.x & 63;
    u64 lmask_lt = (lane == 63) ? 0x7FFFFFFFFFFFFFFFull : ((1ull << lane) - 1ull);
    u64 mb[NB];
    #pragma unroll
    for (int b = 0; b < NB; b++) {
        mb[b] = __ballot(ispeak && (c.x == b));
        if (lane == 0) wcnt[w][b] = __popcll(mb[b]);
    }
    __syncthreads();
    if (threadIdx.x < NB) {
        int b = threadIdx.x;
        int tot = wcnt[0][b] + wcnt[1][b] + wcnt[2][b] + wcnt[3][b];
        bbase[b] = tot > 0 ? atomicAdd(&cnt[b * CPAD], tot) : 0;
    }
    __syncthreads();
    if (ispeak) {
        int b = c.x;
        int pre = 0;
        for (int w2 = 0; w2 < w; w2++) pre += wcnt[w2][b];
        int rank = __popcll(mb[b] & lmask_lt);
        int pidx = bbase[b] + pre + rank;
        if (pidx < pcap)
            peaks[(size_t)b * pcap + pidx] =
                ((u64)__float_as_uint(conf) << 32) | (u32)(~(u32)i);
    }
}

// Two-phase LDS-staged streaming GEMV: voxel_desc = l2norm(feats @ W + b).
// 2 waves/block; wave owns 64 rows; features staged 32 cols at a time ->
// 8.4KB LDS per wave, 16.9KB/block -> 9 blocks/CU (18 waves, 56% occ).
// Buffers are wave-private: no __syncthreads at all.
__global__ __launch_bounds__(128) void k_desc(const float* __restrict__ feats,
                       const float* __restrict__ W, const float* __restrict__ bias,
                       float* __restrict__ voxel_desc, int N) {
    __shared__ float lw[2][64 * 33];
    int w = threadIdx.x >> 6;
    int lane = threadIdx.x & 63;
    int tile = blockIdx.x * 2 + w;
    int r0 = tile * 64;
    if (r0 >= N) return;
    float* L = lw[w];
    float acc[32];
    #pragma unroll
    for (int d = 0; d < 32; d++) acc[d] = bias[d];
    #pragma unroll
    for (int ph = 0; ph < 2; ph++) {
        // stage 64 rows x 32 cols: each instr = 8 rows x 128B = 8 full lines
        #pragma unroll
        for (int k = 0; k < 8; k++) {
            int q = k * 64 + lane;          // [0,512)
            int row = q >> 3, col4 = q & 7;
            float4 v = {0.f, 0.f, 0.f, 0.f};
            if (r0 + row < N)
                v = *(const float4*)(feats + (size_t)(r0 + row) * 64 + ph * 32 + col4 * 4);
            float* dst = L + row * 33 + col4 * 4;   // bank (row+4c+e)%32: 2-way, free
            dst[0] = v.x; dst[1] = v.y; dst[2] = v.z; dst[3] = v.w;
        }
        // wave-private staging: compiler's lgkmcnt ordering suffices, no barrier
        const float* f = L + lane * 33;             // bank (lane+c)%32: 2-way, free
        #pragma unroll
        for (int c4 = 0; c4 < 8; c4++) {
            float f0 = f[c4 * 4 + 0], f1 = f[c4 * 4 + 1];
            float f2 = f[c4 * 4 + 2], f3 = f[c4 * 4 + 3];
            const float* Wb = W + (ph * 32 + c4 * 4) * 32;
            #pragma unroll
            for (int d = 0; d < 32; d++) {
                acc[d] = fmaf(f0, Wb[d], acc[d]);
                acc[d] = fmaf(f1, Wb[32 + d], acc[d]);
                acc[d] = fmaf(f2, Wb[64 + d], acc[d]);
                acc[d] = fmaf(f3, Wb[96 + d], acc[d]);
            }
        }
    }
    int i = r0 + lane;
    if (i >= N) return;
    float ss = 0.f;
    #pragma unroll
    for (int d = 0; d < 32; d++) ss += acc[d] * acc[d];
    float inv = 1.0f / fmaxf(sqrtf(ss), 1e-12f);
    float4* out4 = (float4*)(voxel_desc + (size_t)i * 32);
    #pragma unroll
    for (int q = 0; q < 8; q++) {
        float4 o;
        o.x = acc[q * 4 + 0] * inv; o.y = acc[q * 4 + 1] * inv;
        o.z = acc[q * 4 + 2] * inv; o.w = acc[q * 4 + 3] * inv;
        out4[q] = o;   // each lane writes exactly one full 128B line
    }
}

// One block; wave b finds per-batch threshold bin (count of bins >= thr covers K).
__global__ void k_thresh(const int* __restrict__ hist, const int* __restrict__ cnt,
                         u32* __restrict__ thrbin, int pcap) {
    int w = threadIdx.x >> 6;
    int lane = threadIdx.x & 63;
    if (w >= NB) return;
    int n = cnt[w * CPAD]; if (n > pcap) n = pcap;
    int need = n < KSEL ? n : KSEL;
    const int* h = hist + w * NBINS;
    int running = 0;
    u32 thr = 0;
    for (int hi = NBINS - 64; hi >= 0; hi -= 64) {
        int v = h[hi + lane];
        int s = v;   // inclusive suffix scan
        #pragma unroll
        for (int off = 1; off < 64; off <<= 1) {
            int o = __shfl_down(s, off);
            if (lane + off < 64) s += o;
        }
        int csum = __shfl(s, 0);
        if (running + csum >= need) {
            u64 m = __ballot(running + s >= need);
            int top = 63 - __builtin_clzll(m);
            thr = (u32)(hi + top);
            break;
        }
        running += csum;
    }
    if (lane == 0) thrbin[w] = thr;
}

__global__ void k_compact(const u64* __restrict__ peaks, const int* __restrict__ cnt,
                          const u32* __restrict__ thrbin, u64* __restrict__ cand,
                          int* __restrict__ ccnt, int pcap) {
    int t = blockIdx.x * blockDim.x + threadIdx.x;
    int b = t / pcap;
    if (b >= NB) return;
    int e = t % pcap;
    int n = cnt[b * CPAD]; if (n > pcap) n = pcap;
    if (e >= n) return;
    u64 key = peaks[(size_t)b * pcap + e];
    float conf = __uint_as_float((u32)(key >> 32));
    if (conf_bin(conf) >= (int)thrbin[b]) {
        int p = atomicAdd(&ccnt[b * CPAD], 1);
        if (p < CAND_CAP) cand[(size_t)b * CAND_CAP + p] = key;
    }
}

// Per-batch exact top-K over the small candidate set (radix select + bitonic sort).
__global__ void k_topk(u64* __restrict__ cand, const int* __restrict__ ccnt,
                       u64* __restrict__ bufA, u64* __restrict__ selected) {
    int b = blockIdx.x;
    int tid = threadIdx.x;
    __shared__ int hist[256];
    __shared__ int sh_split, sh_above, sh_selc, sh_candc;
    u64* sel = selected + b * KSEL;
    u64* pcur = cand + (size_t)b * CAND_CAP;
    u64* pnxt = bufA + (size_t)b * CAND_CAP;
    int n = ccnt[b * CPAD];
    if (n > CAND_CAP) n = CAND_CAP;
    int need = KSEL, nsel = 0;

    for (int byte = 7; byte >= 0; byte--) {
        if (need <= 0) break;
        if (n <= need) {
            for (int idx = tid; idx < n; idx += blockDim.x) sel[nsel + idx] = pcur[idx];
            nsel += n; need -= n; n = 0;
            break;
        }
        hist[tid] = 0;
        __syncthreads();
        int shift = byte * 8;
        for (int idx = tid; idx < n; idx += blockDim.x)
            atomicAdd(&hist[(int)((pcur[idx] >> shift) & 255)], 1);
        __syncthreads();
        if (tid == 0) {
            int above = 0, s = 255;
            for (; s > 0; s--) {
                if (above + hist[s] >= need) break;
                above += hist[s];
            }
            sh_split = s; sh_above = above; sh_selc = 0; sh_candc = 0;
        }
        __syncthreads();
        int s = sh_split;
        for (int idx = tid; idx < n; idx += blockDim.x) {
            u64 e = pcur[idx];
            int bv = (int)((e >> shift) & 255);
            if (bv > s) { int p = atomicAdd(&sh_selc, 1); sel[nsel + p] = e; }
            else if (bv == s) { int p = atomicAdd(&sh_candc, 1); pnxt[p] = e; }
        }
        __syncthreads();
        nsel += sh_above; need -= sh_above; n = sh_candc;
        u64* t = pcur; pcur = pnxt; pnxt = t;
        __syncthreads();
    }
    if (need > 0 && n > 0) {
        int take = need < n ? need : n;
        for (int idx = tid; idx < take; idx += blockDim.x) sel[nsel + idx] = pcur[idx];
        nsel += take;
    }
    for (int idx = nsel + tid; idx < KSEL; idx += blockDim.x) sel[idx] = 0;
    __syncthreads();

    __shared__ u64 sk[KSEL];
    if (tid < KSEL) sk[tid] = sel[tid];
    __syncthreads();
    for (int k = 2; k <= KSEL; k <<= 1) {
        for (int j = k >> 1; j > 0; j >>= 1) {
            if (tid < KSEL) {
                int ixj = tid ^ j;
                if (ixj > tid) {
                    u64 a = sk[tid], c2 = sk[ixj];
                    bool upper = (tid & k) != 0;
                    if (upper ? (a > c2) : (a < c2)) { sk[tid] = c2; sk[ixj] = a; }
                }
            }
            __syncthreads();
        }
    }
    if (tid < KSEL) sel[tid] = sk[tid];
}

// Wave-per-peak finalize: parallel probes, coalesced feats gather, shfl GEMV.
__global__ void k_final(const int* __restrict__ coords, const float* __restrict__ feats,
                        const float* __restrict__ scores, const float* __restrict__ W,
                        const float* __restrict__ bias, const float* __restrict__ background,
                        const u64* __restrict__ tab, const u64* __restrict__ selected,
                        float* __restrict__ out, int N) {
    int gw = (blockIdx.x * blockDim.x + threadIdx.x) >> 6;
    int lane = threadIdx.x & 63;
    float* full = out + NB * KSEL + (size_t)N * 32;
    if (gw >= NB * KSEL) {
        int b = gw - NB * KSEL;
        if (b < NB && lane < 32)
            full[(size_t)(b * (KSEL + 1)) * 32 + lane] = background[lane];
        return;
    }
    int b = gw >> 7, k = gw & 127;
    u64 key = selected[gw];
    float* row = full + (size_t)(b * (KSEL + 1) + 1 + k) * 32;
    if (key == 0ull) {
        if (lane == 0) out[gw] = 0.f;
        if (lane < 32) row[lane] = 0.f;
        return;
    }
    float conf = __uint_as_float((u32)(key >> 32));
    int i = (int)(~(u32)key);
    if (lane == 0) out[gw] = conf;
    int4 c = ((const int4*)coords)[i];
    int kb = ((c.x * S + c.y) * S + c.z) * S + c.w;
    int j = -1; bool hit = false;
    if (lane < 27) {
        int dx = lane / 9 - 1, r = lane % 9;
        int dy = r / 3 - 1, dz = r % 3 - 1;
        int nx = c.y + dx, ny = c.z + dy, nz = c.w + dz;
        if ((unsigned)nx < S && (unsigned)ny < S && (unsigned)nz < S) {
            j = tab_lookup(tab, kb + dx * (S * S) + dy * S + dz);
            if (j >= 0) hit = scores[j] > TAU;
        }
    }
    u64 hm = __ballot(hit);
    int c27 = __popcll(hm);
    float fsum = 0.f;
    u64 m = hm;
    while (m) {
        int src = __ffsll((long long)m) - 1;
        m &= m - 1;
        int jj = __shfl(j, src);
        fsum += feats[(size_t)jj * 64 + lane];
    }
    float favg = fsum / fmaxf((float)c27, 1.0f);
    int d = lane & 31;
    float acc = bias[d];
    #pragma unroll
    for (int l = 0; l < 64; l++) {
        float fl = __shfl(favg, l);
        acc = fmaf(fl, W[l * 32 + d], acc);
    }
    float ss = acc * acc;
    #pragma unroll
    for (int off = 1; off < 32; off <<= 1) ss += __shfl_xor(ss, off);
    float inv = 1.0f / fmaxf(sqrtf(ss), 1e-12f);
    if (lane < 32) row[lane] = acc * inv;
}

extern "C" void kernel_launch(void* const* d_in, const int* in_sizes, int n_in,
                              void* d_out, int out_size, void* d_ws, size_t ws_size,
                              hipStream_t stream) {
    const int* coords = (const int*)d_in[0];
    const float* feats = (const float*)d_in[1];
    const float* scores = (const float*)d_in[2];
    const float* W = (const float*)d_in[3];
    const float* bias = (const float*)d_in[4];
    const float* background = (const float*)d_in[5];
    int N = in_sizes[0] / 4;
    float* out = (float*)d_out;
    int pcap = N / 2;

    char* ws = (char*)d_ws;
    size_t off = 0;
    u64* tab = (u64*)(ws + off); off += (size_t)TAB_SZ * 8;
    u32* bm = (u32*)(ws + off); off += (size_t)BM_WORDS * 4;
    int* hist = (int*)(ws + off); off += (size_t)NB * NBINS * 4;
    int* cnt = (int*)(ws + off); off += (size_t)NB * CPAD * 4;
    int* ccnt = (int*)(ws + off); off += (size_t)NB * CPAD * 4;
    u32* thrbin = (u32*)(ws + off); off += 256;
    u64* peaks = (u64*)(ws + off); off += (size_t)NB * pcap * 8;
    u64* cand = (u64*)(ws + off); off += (size_t)NB * CAND_CAP * 8;
    u64* bufA = (u64*)(ws + off); off += (size_t)NB * CAND_CAP * 8;
    u64* selected = (u64*)(ws + off); off += (size_t)NB * KSEL * 8;

    int nTiles = (N + 63) / 64;
    k_init<<<TAB_SZ / 256, 256, 0, stream>>>(tab, bm, cnt, hist, ccnt, thrbin);
    k_insert<<<(N + 255) / 256, 256, 0, stream>>>(coords, scores, tab, bm, N);
    k_peak<<<(N + 255) / 256, 256, 0, stream>>>(coords, scores, tab, bm,
                                                peaks, cnt, hist, N, pcap);
    k_desc<<<(nTiles + 1) / 2, 128, 0, stream>>>(feats, W, bias, out + NB * KSEL, N);
    k_thresh<<<1, 256, 0, stream>>>(hist, cnt, thrbin, pcap);
    k_compact<<<(NB * pcap + 255) / 256, 256, 0, stream>>>(peaks, cnt, thrbin, cand, ccnt, pcap);
    k_topk<<<NB, 256, 0, stream>>>(cand, ccnt, bufA, selected);
    k_final<<<(NB * KSEL + NB + 3) / 4, 256, 0, stream>>>(coords, feats, scores, W, bias,
                                                          background, tab, selected, out, N);
}

// Round 8
// 363.605 us; speedup vs baseline: 1.0154x; 1.0154x over previous
//
#include <hip/hip_runtime.h>
#include <math.h>

#define S 256
#define NB 4
#define TAU 0.1f
#define KSEL 128
#define LOG_TAB 21
#define TAB_SZ (1u << LOG_TAB)
#define TAB_MASK (TAB_SZ - 1)
#define EMPTY64 0xFFFFFFFFFFFFFFFFull
#define BM_WORDS (1u << 21)   // 4*256^3 bits / 32
#define NBINS 8192
#define BIN_BASE 0x3D800      // (0x3D800000 >> 12), conf floor 0.0625 < TAU
#define CAND_CAP 4096
#define CPAD 32               // ints per counter slot -> one 128B line each

typedef unsigned long long u64;
typedef unsigned int u32;

__device__ __forceinline__ u32 hash_key(int key) {
    u32 h = (u32)key * 0x9E3779B1u;
    h ^= h >> 15;
    return h & TAB_MASK;
}

__device__ __forceinline__ int conf_bin(float conf) {
    int bin = (int)(__float_as_uint(conf) >> 12) - BIN_BASE;
    return bin < 0 ? 0 : (bin > NBINS - 1 ? NBINS - 1 : bin);
}

// Insert (key -> min index) AND set bm bit with own conf. bm = OR over dups with
// conf>TAU: superset of "rep conf>TAU"; false positives only ever add cj<=TAU<conf
// to hmax, which cannot change the (hmax==conf) peak decision.
__global__ void k_insert(const int* __restrict__ coords, const float* __restrict__ scores,
                         u64* __restrict__ tab, u32* __restrict__ bm, int N) {
    int i = blockIdx.x * blockDim.x + threadIdx.x;
    if (i >= N) return;
    int4 c = ((const int4*)coords)[i];
    float conf = scores[i];
    int key = ((c.x * S + c.y) * S + c.z) * S + c.w;
    if (conf > TAU) atomicOr(&bm[(u32)key >> 5], 1u << (key & 31));
    u64 ins = ((u64)(u32)key << 32) | (u32)i;
    u32 slot = hash_key(key);
    for (;;) {
        u64 e = tab[slot];
        if ((u32)(e >> 32) == (u32)key) { atomicMin(&tab[slot], ins); return; }
        if (e == EMPTY64) {
            u64 prev = atomicCAS(&tab[slot], EMPTY64, ins);
            if (prev == EMPTY64) return;
            if ((u32)(prev >> 32) == (u32)key) { atomicMin(&tab[slot], ins); return; }
        }
        slot = (slot + 1) & TAB_MASK;
    }
}

__device__ __forceinline__ int tab_lookup(const u64* __restrict__ tab, int key) {
    u32 slot = hash_key(key);
    for (;;) {
        u64 e = tab[slot];
        if ((u32)(e >> 32) == (u32)key) return (int)(u32)e;
        if (e == EMPTY64) return -1;
        slot = (slot + 1) & TAB_MASK;
    }
}

// Peak detect (z-packed bitmask + sparse probes) + hist + block-aggregated compaction.
__global__ void k_peak(const int* __restrict__ coords, const float* __restrict__ scores,
                       const u64* __restrict__ tab, const u32* __restrict__ bm,
                       u64* __restrict__ peaks, int* __restrict__ cnt, int* __restrict__ hist,
                       int N, int pcap) {
    int i = blockIdx.x * blockDim.x + threadIdx.x;
    bool alive = (i < N);
    int ii = alive ? i : 0;
    int4 c = ((const int4*)coords)[ii];
    float conf = alive ? scores[ii] : -1.0f;
    int kb = ((c.x * S + c.y) * S + c.z) * S + c.w;
    bool ispeak = false;
    if (alive && conf > TAU) {
        u32 m27 = 0;
        u32 vzm = (u32)((c.w > 0) ? 1 : 0) | 2u | (u32)((c.w < S - 1) ? 4 : 0);
        #pragma unroll
        for (int dx = -1; dx <= 1; dx++) {
            if ((unsigned)(c.y + dx) >= S) continue;
            #pragma unroll
            for (int dy = -1; dy <= 1; dy++) {
                if ((unsigned)(c.z + dy) >= S) continue;
                int nk = kb + dx * (S * S) + dy * S;   // center-z key of this column
                u32 idx = (u32)nk >> 5;
                int sft = nk & 31;
                u32 w0 = bm[idx];
                u32 b3;
                if (sft >= 1 && sft <= 30) {
                    b3 = (w0 >> (sft - 1)) & 7u;
                } else if (sft == 0) {
                    u32 wm = (nk >= 32) ? bm[idx - 1] : 0u;
                    b3 = ((wm >> 31) & 1u) | ((w0 & 3u) << 1);
                } else { // sft == 31
                    u32 wp = (idx + 1 < BM_WORDS) ? bm[idx + 1] : 0u;
                    b3 = ((w0 >> 30) & 3u) | ((wp & 1u) << 2);
                }
                b3 &= vzm;
                int p = ((dx + 1) * 3 + (dy + 1)) * 3;
                m27 |= b3 << p;
            }
        }
        float hmax = -INFINITY;
        while (m27) {
            int q = __builtin_ctz(m27);
            m27 &= m27 - 1;
            int dx = q / 9 - 1;
            int r = q % 9;
            int dy = r / 3 - 1, dz = r % 3 - 1;
            int j = tab_lookup(tab, kb + dx * (S * S) + dy * S + dz);
            if (j >= 0) hmax = fmaxf(hmax, scores[j]); // cj<=TAU contributions harmless
        }
        ispeak = (hmax == conf);
    }

    if (ispeak) atomicAdd(&hist[c.x * NBINS + conf_bin(conf)], 1);

    // block-aggregated compaction: 4 padded atomics per BLOCK
    __shared__ int wcnt[4][NB];
    __shared__ int bbase[NB];
    int w = threadIdx.x >> 6;
    int lane = threadIdx.x & 63;
    u64 lmask_lt = (lane == 63) ? 0x7FFFFFFFFFFFFFFFull : ((1ull << lane) - 1ull);
    u64 mb[NB];
    #pragma unroll
    for (int b = 0; b < NB; b++) {
        mb[b] = __ballot(ispeak && (c.x == b));
        if (lane == 0) wcnt[w][b] = __popcll(mb[b]);
    }
    __syncthreads();
    if (threadIdx.x < NB) {
        int b = threadIdx.x;
        int tot = wcnt[0][b] + wcnt[1][b] + wcnt[2][b] + wcnt[3][b];
        bbase[b] = tot > 0 ? atomicAdd(&cnt[b * CPAD], tot) : 0;
    }
    __syncthreads();
    if (ispeak) {
        int b = c.x;
        int pre = 0;
        for (int w2 = 0; w2 < w; w2++) pre += wcnt[w2][b];
        int rank = __popcll(mb[b] & lmask_lt);
        int pidx = bbase[b] + pre + rank;
        if (pidx < pcap)
            peaks[(size_t)b * pcap + pidx] =
                ((u64)__float_as_uint(conf) << 32) | (u32)(~(u32)i);
    }
}

// Pipelined LDS-staged streaming GEMV: voxel_desc = l2norm(feats @ W + b).
// Block tile = 256 rows; 4 phases x 16 cols; register-prefetch next phase's
// global loads BEFORE the compute of the current phase, so ~1024 cycles of FMA
// hide the L2/HBM latency. LDS 17.4KB/block -> ~7 blocks/CU (~28 waves, 87%).
__global__ __launch_bounds__(256) void k_desc(const float* __restrict__ feats,
                       const float* __restrict__ W, const float* __restrict__ bias,
                       float* __restrict__ voxel_desc, int N) {
    __shared__ float L[256 * 17];
    int t = threadIdx.x;
    int R0 = blockIdx.x * 256;
    float acc[32];
    #pragma unroll
    for (int d = 0; d < 32; d++) acc[d] = bias[d];

    int q_row[4], q_c4[4];
    #pragma unroll
    for (int k = 0; k < 4; k++) {
        int q = k * 256 + t;
        q_row[k] = q >> 2;
        q_c4[k] = q & 3;
    }
    float4 v[4];
    #pragma unroll
    for (int k = 0; k < 4; k++) {
        int r = R0 + q_row[k];
        v[k] = (r < N) ? *(const float4*)(feats + (size_t)r * 64 + q_c4[k] * 4)
                       : float4{0.f, 0.f, 0.f, 0.f};
    }
    #pragma unroll
    for (int p = 0; p < 4; p++) {
        __syncthreads();   // previous phase's LDS consumers done
        #pragma unroll
        for (int k = 0; k < 4; k++) {
            float* dst = L + q_row[k] * 17 + q_c4[k] * 4;
            dst[0] = v[k].x; dst[1] = v[k].y; dst[2] = v[k].z; dst[3] = v[k].w;
        }
        if (p < 3) {
            #pragma unroll
            for (int k = 0; k < 4; k++) {
                int r = R0 + q_row[k];
                v[k] = (r < N) ? *(const float4*)(feats + (size_t)r * 64 + (p + 1) * 16 + q_c4[k] * 4)
                               : float4{0.f, 0.f, 0.f, 0.f};
            }
        }
        __syncthreads();   // staged data visible; prefetch loads remain in flight
        const float* f = L + t * 17;   // bank (17t+c)%32: exactly 2-way, free
        #pragma unroll
        for (int c = 0; c < 16; c += 4) {
            float f0 = f[c], f1 = f[c + 1], f2 = f[c + 2], f3 = f[c + 3];
            const float* Wb = W + (p * 16 + c) * 32;   // thread-uniform -> s_load
            #pragma unroll
            for (int d = 0; d < 32; d++) {
                acc[d] = fmaf(f0, Wb[d], acc[d]);
                acc[d] = fmaf(f1, Wb[32 + d], acc[d]);
                acc[d] = fmaf(f2, Wb[64 + d], acc[d]);
                acc[d] = fmaf(f3, Wb[96 + d], acc[d]);
            }
        }
    }
    int i = R0 + t;
    if (i >= N) return;
    float ss = 0.f;
    #pragma unroll
    for (int d = 0; d < 32; d++) ss += acc[d] * acc[d];
    float inv = 1.0f / fmaxf(sqrtf(ss), 1e-12f);
    float4* out4 = (float4*)(voxel_desc + (size_t)i * 32);
    #pragma unroll
    for (int q = 0; q < 8; q++) {
        float4 o;
        o.x = acc[q * 4 + 0] * inv; o.y = acc[q * 4 + 1] * inv;
        o.z = acc[q * 4 + 2] * inv; o.w = acc[q * 4 + 3] * inv;
        out4[q] = o;   // each lane writes exactly one full 128B line
    }
}

// One block; wave b finds per-batch threshold bin (count of bins >= thr covers K).
__global__ void k_thresh(const int* __restrict__ hist, const int* __restrict__ cnt,
                         u32* __restrict__ thrbin, int pcap) {
    int w = threadIdx.x >> 6;
    int lane = threadIdx.x & 63;
    if (w >= NB) return;
    int n = cnt[w * CPAD]; if (n > pcap) n = pcap;
    int need = n < KSEL ? n : KSEL;
    const int* h = hist + w * NBINS;
    int running = 0;
    u32 thr = 0;
    for (int hi = NBINS - 64; hi >= 0; hi -= 64) {
        int v = h[hi + lane];
        int s = v;   // inclusive suffix scan
        #pragma unroll
        for (int off = 1; off < 64; off <<= 1) {
            int o = __shfl_down(s, off);
            if (lane + off < 64) s += o;
        }
        int csum = __shfl(s, 0);
        if (running + csum >= need) {
            u64 m = __ballot(running + s >= need);
            int top = 63 - __builtin_clzll(m);
            thr = (u32)(hi + top);
            break;
        }
        running += csum;
    }
    if (lane == 0) thrbin[w] = thr;
}

__global__ void k_compact(const u64* __restrict__ peaks, const int* __restrict__ cnt,
                          const u32* __restrict__ thrbin, u64* __restrict__ cand,
                          int* __restrict__ ccnt, int pcap) {
    int t = blockIdx.x * blockDim.x + threadIdx.x;
    int b = t / pcap;
    if (b >= NB) return;
    int e = t % pcap;
    int n = cnt[b * CPAD]; if (n > pcap) n = pcap;
    if (e >= n) return;
    u64 key = peaks[(size_t)b * pcap + e];
    float conf = __uint_as_float((u32)(key >> 32));
    if (conf_bin(conf) >= (int)thrbin[b]) {
        int p = atomicAdd(&ccnt[b * CPAD], 1);
        if (p < CAND_CAP) cand[(size_t)b * CAND_CAP + p] = key;
    }
}

// Per-batch exact top-K over the small candidate set (radix select + bitonic sort).
__global__ void k_topk(u64* __restrict__ cand, const int* __restrict__ ccnt,
                       u64* __restrict__ bufA, u64* __restrict__ selected) {
    int b = blockIdx.x;
    int tid = threadIdx.x;
    __shared__ int hist[256];
    __shared__ int sh_split, sh_above, sh_selc, sh_candc;
    u64* sel = selected + b * KSEL;
    u64* pcur = cand + (size_t)b * CAND_CAP;
    u64* pnxt = bufA + (size_t)b * CAND_CAP;
    int n = ccnt[b * CPAD];
    if (n > CAND_CAP) n = CAND_CAP;
    int need = KSEL, nsel = 0;

    for (int byte = 7; byte >= 0; byte--) {
        if (need <= 0) break;
        if (n <= need) {
            for (int idx = tid; idx < n; idx += blockDim.x) sel[nsel + idx] = pcur[idx];
            nsel += n; need -= n; n = 0;
            break;
        }
        hist[tid] = 0;
        __syncthreads();
        int shift = byte * 8;
        for (int idx = tid; idx < n; idx += blockDim.x)
            atomicAdd(&hist[(int)((pcur[idx] >> shift) & 255)], 1);
        __syncthreads();
        if (tid == 0) {
            int above = 0, s = 255;
            for (; s > 0; s--) {
                if (above + hist[s] >= need) break;
                above += hist[s];
            }
            sh_split = s; sh_above = above; sh_selc = 0; sh_candc = 0;
        }
        __syncthreads();
        int s = sh_split;
        for (int idx = tid; idx < n; idx += blockDim.x) {
            u64 e = pcur[idx];
            int bv = (int)((e >> shift) & 255);
            if (bv > s) { int p = atomicAdd(&sh_selc, 1); sel[nsel + p] = e; }
            else if (bv == s) { int p = atomicAdd(&sh_candc, 1); pnxt[p] = e; }
        }
        __syncthreads();
        nsel += sh_above; need -= sh_above; n = sh_candc;
        u64* t = pcur; pcur = pnxt; pnxt = t;
        __syncthreads();
    }
    if (need > 0 && n > 0) {
        int take = need < n ? need : n;
        for (int idx = tid; idx < take; idx += blockDim.x) sel[nsel + idx] = pcur[idx];
        nsel += take;
    }
    for (int idx = nsel + tid; idx < KSEL; idx += blockDim.x) sel[idx] = 0;
    __syncthreads();

    __shared__ u64 sk[KSEL];
    if (tid < KSEL) sk[tid] = sel[tid];
    __syncthreads();
    for (int k = 2; k <= KSEL; k <<= 1) {
        for (int j = k >> 1; j > 0; j >>= 1) {
            if (tid < KSEL) {
                int ixj = tid ^ j;
                if (ixj > tid) {
                    u64 a = sk[tid], c2 = sk[ixj];
                    bool upper = (tid & k) != 0;
                    if (upper ? (a > c2) : (a < c2)) { sk[tid] = c2; sk[ixj] = a; }
                }
            }
            __syncthreads();
        }
    }
    if (tid < KSEL) sel[tid] = sk[tid];
}

// Wave-per-peak finalize: parallel probes, coalesced feats gather, shfl GEMV.
__global__ void k_final(const int* __restrict__ coords, const float* __restrict__ feats,
                        const float* __restrict__ scores, const float* __restrict__ W,
                        const float* __restrict__ bias, const float* __restrict__ background,
                        const u64* __restrict__ tab, const u64* __restrict__ selected,
                        float* __restrict__ out, int N) {
    int gw = (blockIdx.x * blockDim.x + threadIdx.x) >> 6;
    int lane = threadIdx.x & 63;
    float* full = out + NB * KSEL + (size_t)N * 32;
    if (gw >= NB * KSEL) {
        int b = gw - NB * KSEL;
        if (b < NB && lane < 32)
            full[(size_t)(b * (KSEL + 1)) * 32 + lane] = background[lane];
        return;
    }
    int b = gw >> 7, k = gw & 127;
    u64 key = selected[gw];
    float* row = full + (size_t)(b * (KSEL + 1) + 1 + k) * 32;
    if (key == 0ull) {
        if (lane == 0) out[gw] = 0.f;
        if (lane < 32) row[lane] = 0.f;
        return;
    }
    float conf = __uint_as_float((u32)(key >> 32));
    int i = (int)(~(u32)key);
    if (lane == 0) out[gw] = conf;
    int4 c = ((const int4*)coords)[i];
    int kb = ((c.x * S + c.y) * S + c.z) * S + c.w;
    int j = -1; bool hit = false;
    if (lane < 27) {
        int dx = lane / 9 - 1, r = lane % 9;
        int dy = r / 3 - 1, dz = r % 3 - 1;
        int nx = c.y + dx, ny = c.z + dy, nz = c.w + dz;
        if ((unsigned)nx < S && (unsigned)ny < S && (unsigned)nz < S) {
            j = tab_lookup(tab, kb + dx * (S * S) + dy * S + dz);
            if (j >= 0) hit = scores[j] > TAU;
        }
    }
    u64 hm = __ballot(hit);
    int c27 = __popcll(hm);
    float fsum = 0.f;
    u64 m = hm;
    while (m) {
        int src = __ffsll((long long)m) - 1;
        m &= m - 1;
        int jj = __shfl(j, src);
        fsum += feats[(size_t)jj * 64 + lane];
    }
    float favg = fsum / fmaxf((float)c27, 1.0f);
    int d = lane & 31;
    float acc = bias[d];
    #pragma unroll
    for (int l = 0; l < 64; l++) {
        float fl = __shfl(favg, l);
        acc = fmaf(fl, W[l * 32 + d], acc);
    }
    float ss = acc * acc;
    #pragma unroll
    for (int off = 1; off < 32; off <<= 1) ss += __shfl_xor(ss, off);
    float inv = 1.0f / fmaxf(sqrtf(ss), 1e-12f);
    if (lane < 32) row[lane] = acc * inv;
}

extern "C" void kernel_launch(void* const* d_in, const int* in_sizes, int n_in,
                              void* d_out, int out_size, void* d_ws, size_t ws_size,
                              hipStream_t stream) {
    const int* coords = (const int*)d_in[0];
    const float* feats = (const float*)d_in[1];
    const float* scores = (const float*)d_in[2];
    const float* W = (const float*)d_in[3];
    const float* bias = (const float*)d_in[4];
    const float* background = (const float*)d_in[5];
    int N = in_sizes[0] / 4;
    float* out = (float*)d_out;
    int pcap = N / 2;

    char* ws = (char*)d_ws;
    size_t off = 0;
    u64* tab = (u64*)(ws + off); off += (size_t)TAB_SZ * 8;
    // zero-region start: bm, hist, cnt, ccnt, thrbin contiguous
    size_t zoff = off;
    u32* bm = (u32*)(ws + off); off += (size_t)BM_WORDS * 4;
    int* hist = (int*)(ws + off); off += (size_t)NB * NBINS * 4;
    int* cnt = (int*)(ws + off); off += (size_t)NB * CPAD * 4;
    int* ccnt = (int*)(ws + off); off += (size_t)NB * CPAD * 4;
    u32* thrbin = (u32*)(ws + off); off += 256;
    size_t zlen = off - zoff;
    u64* peaks = (u64*)(ws + off); off += (size_t)NB * pcap * 8;
    u64* cand = (u64*)(ws + off); off += (size_t)NB * CAND_CAP * 8;
    u64* bufA = (u64*)(ws + off); off += (size_t)NB * CAND_CAP * 8;
    u64* selected = (u64*)(ws + off); off += (size_t)NB * KSEL * 8;

    hipMemsetAsync(tab, 0xFF, (size_t)TAB_SZ * 8, stream);   // EMPTY64
    hipMemsetAsync(ws + zoff, 0, zlen, stream);              // bm/hist/cnt/ccnt/thrbin
    k_insert<<<(N + 255) / 256, 256, 0, stream>>>(coords, scores, tab, bm, N);
    k_peak<<<(N + 255) / 256, 256, 0, stream>>>(coords, scores, tab, bm,
                                                peaks, cnt, hist, N, pcap);
    k_desc<<<(N + 255) / 256, 256, 0, stream>>>(feats, W, bias, out + NB * KSEL, N);
    k_thresh<<<1, 256, 0, stream>>>(hist, cnt, thrbin, pcap);
    k_compact<<<(NB * pcap + 255) / 256, 256, 0, stream>>>(peaks, cnt, thrbin, cand, ccnt, pcap);
    k_topk<<<NB, 256, 0, stream>>>(cand, ccnt, bufA, selected);
    k_final<<<(NB * KSEL + NB + 3) / 4, 256, 0, stream>>>(coords, feats, scores, W, bias,
                                                          background, tab, selected, out, N);
}

// Round 9
// 357.604 us; speedup vs baseline: 1.0324x; 1.0168x over previous
//
#include <hip/hip_runtime.h>
#include <math.h>

#define S 256
#define NB 4
#define TAU 0.1f
#define KSEL 128
#define LOG_TAB 21
#define TAB_SZ (1u << LOG_TAB)
#define TAB_MASK (TAB_SZ - 1)
#define EMPTY64 0xFFFFFFFFFFFFFFFFull
#define BM_WORDS (1u << 21)   // 4*256^3 bits / 32
#define NBINS 8192
#define BIN_BASE 0x3D800      // (0x3D800000 >> 12), conf floor 0.0625 < TAU
#define CAND_CAP 4096
#define CPAD 32               // ints per counter slot -> one 128B line each

typedef unsigned long long u64;
typedef unsigned int u32;

__device__ __forceinline__ u32 hash_key(int key) {
    u32 h = (u32)key * 0x9E3779B1u;
    h ^= h >> 15;
    return h & TAB_MASK;
}

__device__ __forceinline__ int conf_bin(float conf) {
    int bin = (int)(__float_as_uint(conf) >> 12) - BIN_BASE;
    return bin < 0 ? 0 : (bin > NBINS - 1 ? NBINS - 1 : bin);
}

// Insert (key -> min index) AND set bm bit with own conf. bm = OR over dups with
// conf>TAU: superset of "rep conf>TAU"; false positives only ever add cj<=TAU<conf
// to hmax, which cannot change the (hmax==conf) peak decision.
__global__ void k_insert(const int* __restrict__ coords, const float* __restrict__ scores,
                         u64* __restrict__ tab, u32* __restrict__ bm, int N) {
    int i = blockIdx.x * blockDim.x + threadIdx.x;
    if (i >= N) return;
    int4 c = ((const int4*)coords)[i];
    float conf = scores[i];
    int key = ((c.x * S + c.y) * S + c.z) * S + c.w;
    if (conf > TAU) atomicOr(&bm[(u32)key >> 5], 1u << (key & 31));
    u64 ins = ((u64)(u32)key << 32) | (u32)i;
    u32 slot = hash_key(key);
    for (;;) {
        u64 e = tab[slot];
        if ((u32)(e >> 32) == (u32)key) { atomicMin(&tab[slot], ins); return; }
        if (e == EMPTY64) {
            u64 prev = atomicCAS(&tab[slot], EMPTY64, ins);
            if (prev == EMPTY64) return;
            if ((u32)(prev >> 32) == (u32)key) { atomicMin(&tab[slot], ins); return; }
        }
        slot = (slot + 1) & TAB_MASK;
    }
}

__device__ __forceinline__ int tab_lookup(const u64* __restrict__ tab, int key) {
    u32 slot = hash_key(key);
    for (;;) {
        u64 e = tab[slot];
        if ((u32)(e >> 32) == (u32)key) return (int)(u32)e;
        if (e == EMPTY64) return -1;
        slot = (slot + 1) & TAB_MASK;
    }
}

// Peak detect (z-packed bitmask + sparse probes) + hist + block-aggregated compaction.
__global__ void k_peak(const int* __restrict__ coords, const float* __restrict__ scores,
                       const u64* __restrict__ tab, const u32* __restrict__ bm,
                       u64* __restrict__ peaks, int* __restrict__ cnt, int* __restrict__ hist,
                       int N, int pcap) {
    int i = blockIdx.x * blockDim.x + threadIdx.x;
    bool alive = (i < N);
    int ii = alive ? i : 0;
    int4 c = ((const int4*)coords)[ii];
    float conf = alive ? scores[ii] : -1.0f;
    int kb = ((c.x * S + c.y) * S + c.z) * S + c.w;
    bool ispeak = false;
    if (alive && conf > TAU) {
        u32 m27 = 0;
        u32 vzm = (u32)((c.w > 0) ? 1 : 0) | 2u | (u32)((c.w < S - 1) ? 4 : 0);
        #pragma unroll
        for (int dx = -1; dx <= 1; dx++) {
            if ((unsigned)(c.y + dx) >= S) continue;
            #pragma unroll
            for (int dy = -1; dy <= 1; dy++) {
                if ((unsigned)(c.z + dy) >= S) continue;
                int nk = kb + dx * (S * S) + dy * S;   // center-z key of this column
                u32 idx = (u32)nk >> 5;
                int sft = nk & 31;
                u32 w0 = bm[idx];
                u32 b3;
                if (sft >= 1 && sft <= 30) {
                    b3 = (w0 >> (sft - 1)) & 7u;
                } else if (sft == 0) {
                    u32 wm = (nk >= 32) ? bm[idx - 1] : 0u;
                    b3 = ((wm >> 31) & 1u) | ((w0 & 3u) << 1);
                } else { // sft == 31
                    u32 wp = (idx + 1 < BM_WORDS) ? bm[idx + 1] : 0u;
                    b3 = ((w0 >> 30) & 3u) | ((wp & 1u) << 2);
                }
                b3 &= vzm;
                int p = ((dx + 1) * 3 + (dy + 1)) * 3;
                m27 |= b3 << p;
            }
        }
        float hmax = -INFINITY;
        while (m27) {
            int q = __builtin_ctz(m27);
            m27 &= m27 - 1;
            int dx = q / 9 - 1;
            int r = q % 9;
            int dy = r / 3 - 1, dz = r % 3 - 1;
            int j = tab_lookup(tab, kb + dx * (S * S) + dy * S + dz);
            if (j >= 0) hmax = fmaxf(hmax, scores[j]); // cj<=TAU contributions harmless
        }
        ispeak = (hmax == conf);
    }

    if (ispeak) atomicAdd(&hist[c.x * NBINS + conf_bin(conf)], 1);

    // block-aggregated compaction: 4 padded atomics per BLOCK
    __shared__ int wcnt[4][NB];
    __shared__ int bbase[NB];
    int w = threadIdx.x >> 6;
    int lane = threadIdx.x & 63;
    u64 lmask_lt = (lane == 63) ? 0x7FFFFFFFFFFFFFFFull : ((1ull << lane) - 1ull);
    u64 mb[NB];
    #pragma unroll
    for (int b = 0; b < NB; b++) {
        mb[b] = __ballot(ispeak && (c.x == b));
        if (lane == 0) wcnt[w][b] = __popcll(mb[b]);
    }
    __syncthreads();
    if (threadIdx.x < NB) {
        int b = threadIdx.x;
        int tot = wcnt[0][b] + wcnt[1][b] + wcnt[2][b] + wcnt[3][b];
        bbase[b] = tot > 0 ? atomicAdd(&cnt[b * CPAD], tot) : 0;
    }
    __syncthreads();
    if (ispeak) {
        int b = c.x;
        int pre = 0;
        for (int w2 = 0; w2 < w; w2++) pre += wcnt[w2][b];
        int rank = __popcll(mb[b] & lmask_lt);
        int pidx = bbase[b] + pre + rank;
        if (pidx < pcap)
            peaks[(size_t)b * pcap + pidx] =
                ((u64)__float_as_uint(conf) << 32) | (u32)(~(u32)i);
    }
}

// Register-row streaming GEMV: voxel_desc = l2norm(feats @ W + b).
// No LDS, no barriers: 16 independent float4 loads per thread issued
// back-to-back (one vmcnt wait), then 2048 statically-indexed FMAs from
// registers. ~104 VGPR -> 4 waves/SIMD; 3 waves compute while 1 waits.
__global__ __launch_bounds__(256, 4) void k_desc(const float* __restrict__ feats,
                       const float* __restrict__ W, const float* __restrict__ bias,
                       float* __restrict__ voxel_desc, int N) {
    int i = blockIdx.x * blockDim.x + threadIdx.x;
    if (i >= N) return;
    const float4* row4 = (const float4*)(feats + (size_t)i * 64);
    float4 r[16];
    #pragma unroll
    for (int k = 0; k < 16; k++) r[k] = row4[k];   // 16 loads in flight
    float acc[32];
    #pragma unroll
    for (int d = 0; d < 32; d++) acc[d] = bias[d];
    #pragma unroll
    for (int k = 0; k < 16; k++) {
        float4 f = r[k];
        const float* Wb = W + k * 4 * 32;   // thread-uniform -> scalar loads
        #pragma unroll
        for (int d = 0; d < 32; d++) {
            acc[d] = fmaf(f.x, Wb[d], acc[d]);
            acc[d] = fmaf(f.y, Wb[32 + d], acc[d]);
            acc[d] = fmaf(f.z, Wb[64 + d], acc[d]);
            acc[d] = fmaf(f.w, Wb[96 + d], acc[d]);
        }
    }
    float ss = 0.f;
    #pragma unroll
    for (int d = 0; d < 32; d++) ss += acc[d] * acc[d];
    float inv = 1.0f / fmaxf(sqrtf(ss), 1e-12f);
    float4* out4 = (float4*)(voxel_desc + (size_t)i * 32);
    #pragma unroll
    for (int q = 0; q < 8; q++) {
        float4 o;
        o.x = acc[q * 4 + 0] * inv; o.y = acc[q * 4 + 1] * inv;
        o.z = acc[q * 4 + 2] * inv; o.w = acc[q * 4 + 3] * inv;
        out4[q] = o;   // thread writes exactly its own 128B line
    }
}

// One block; wave b finds per-batch threshold bin (count of bins >= thr covers K).
__global__ void k_thresh(const int* __restrict__ hist, const int* __restrict__ cnt,
                         u32* __restrict__ thrbin, int pcap) {
    int w = threadIdx.x >> 6;
    int lane = threadIdx.x & 63;
    if (w >= NB) return;
    int n = cnt[w * CPAD]; if (n > pcap) n = pcap;
    int need = n < KSEL ? n : KSEL;
    const int* h = hist + w * NBINS;
    int running = 0;
    u32 thr = 0;
    for (int hi = NBINS - 64; hi >= 0; hi -= 64) {
        int v = h[hi + lane];
        int s = v;   // inclusive suffix scan
        #pragma unroll
        for (int off = 1; off < 64; off <<= 1) {
            int o = __shfl_down(s, off);
            if (lane + off < 64) s += o;
        }
        int csum = __shfl(s, 0);
        if (running + csum >= need) {
            u64 m = __ballot(running + s >= need);
            int top = 63 - __builtin_clzll(m);
            thr = (u32)(hi + top);
            break;
        }
        running += csum;
    }
    if (lane == 0) thrbin[w] = thr;
}

__global__ void k_compact(const u64* __restrict__ peaks, const int* __restrict__ cnt,
                          const u32* __restrict__ thrbin, u64* __restrict__ cand,
                          int* __restrict__ ccnt, int pcap) {
    int t = blockIdx.x * blockDim.x + threadIdx.x;
    int b = t / pcap;
    if (b >= NB) return;
    int e = t % pcap;
    int n = cnt[b * CPAD]; if (n > pcap) n = pcap;
    if (e >= n) return;
    u64 key = peaks[(size_t)b * pcap + e];
    float conf = __uint_as_float((u32)(key >> 32));
    if (conf_bin(conf) >= (int)thrbin[b]) {
        int p = atomicAdd(&ccnt[b * CPAD], 1);
        if (p < CAND_CAP) cand[(size_t)b * CAND_CAP + p] = key;
    }
}

// Per-batch exact top-K over the small candidate set (radix select + bitonic sort).
__global__ void k_topk(u64* __restrict__ cand, const int* __restrict__ ccnt,
                       u64* __restrict__ bufA, u64* __restrict__ selected) {
    int b = blockIdx.x;
    int tid = threadIdx.x;
    __shared__ int hist[256];
    __shared__ int sh_split, sh_above, sh_selc, sh_candc;
    u64* sel = selected + b * KSEL;
    u64* pcur = cand + (size_t)b * CAND_CAP;
    u64* pnxt = bufA + (size_t)b * CAND_CAP;
    int n = ccnt[b * CPAD];
    if (n > CAND_CAP) n = CAND_CAP;
    int need = KSEL, nsel = 0;

    for (int byte = 7; byte >= 0; byte--) {
        if (need <= 0) break;
        if (n <= need) {
            for (int idx = tid; idx < n; idx += blockDim.x) sel[nsel + idx] = pcur[idx];
            nsel += n; need -= n; n = 0;
            break;
        }
        hist[tid] = 0;
        __syncthreads();
        int shift = byte * 8;
        for (int idx = tid; idx < n; idx += blockDim.x)
            atomicAdd(&hist[(int)((pcur[idx] >> shift) & 255)], 1);
        __syncthreads();
        if (tid == 0) {
            int above = 0, s = 255;
            for (; s > 0; s--) {
                if (above + hist[s] >= need) break;
                above += hist[s];
            }
            sh_split = s; sh_above = above; sh_selc = 0; sh_candc = 0;
        }
        __syncthreads();
        int s = sh_split;
        for (int idx = tid; idx < n; idx += blockDim.x) {
            u64 e = pcur[idx];
            int bv = (int)((e >> shift) & 255);
            if (bv > s) { int p = atomicAdd(&sh_selc, 1); sel[nsel + p] = e; }
            else if (bv == s) { int p = atomicAdd(&sh_candc, 1); pnxt[p] = e; }
        }
        __syncthreads();
        nsel += sh_above; need -= sh_above; n = sh_candc;
        u64* t = pcur; pcur = pnxt; pnxt = t;
        __syncthreads();
    }
    if (need > 0 && n > 0) {
        int take = need < n ? need : n;
        for (int idx = tid; idx < take; idx += blockDim.x) sel[nsel + idx] = pcur[idx];
        nsel += take;
    }
    for (int idx = nsel + tid; idx < KSEL; idx += blockDim.x) sel[idx] = 0;
    __syncthreads();

    __shared__ u64 sk[KSEL];
    if (tid < KSEL) sk[tid] = sel[tid];
    __syncthreads();
    for (int k = 2; k <= KSEL; k <<= 1) {
        for (int j = k >> 1; j > 0; j >>= 1) {
            if (tid < KSEL) {
                int ixj = tid ^ j;
                if (ixj > tid) {
                    u64 a = sk[tid], c2 = sk[ixj];
                    bool upper = (tid & k) != 0;
                    if (upper ? (a > c2) : (a < c2)) { sk[tid] = c2; sk[ixj] = a; }
                }
            }
            __syncthreads();
        }
    }
    if (tid < KSEL) sel[tid] = sk[tid];
}

// Wave-per-peak finalize: parallel probes, coalesced feats gather, shfl GEMV.
__global__ void k_final(const int* __restrict__ coords, const float* __restrict__ feats,
                        const float* __restrict__ scores, const float* __restrict__ W,
                        const float* __restrict__ bias, const float* __restrict__ background,
                        const u64* __restrict__ tab, const u64* __restrict__ selected,
                        float* __restrict__ out, int N) {
    int gw = (blockIdx.x * blockDim.x + threadIdx.x) >> 6;
    int lane = threadIdx.x & 63;
    float* full = out + NB * KSEL + (size_t)N * 32;
    if (gw >= NB * KSEL) {
        int b = gw - NB * KSEL;
        if (b < NB && lane < 32)
            full[(size_t)(b * (KSEL + 1)) * 32 + lane] = background[lane];
        return;
    }
    int b = gw >> 7, k = gw & 127;
    u64 key = selected[gw];
    float* row = full + (size_t)(b * (KSEL + 1) + 1 + k) * 32;
    if (key == 0ull) {
        if (lane == 0) out[gw] = 0.f;
        if (lane < 32) row[lane] = 0.f;
        return;
    }
    float conf = __uint_as_float((u32)(key >> 32));
    int i = (int)(~(u32)key);
    if (lane == 0) out[gw] = conf;
    int4 c = ((const int4*)coords)[i];
    int kb = ((c.x * S + c.y) * S + c.z) * S + c.w;
    int j = -1; bool hit = false;
    if (lane < 27) {
        int dx = lane / 9 - 1, r = lane % 9;
        int dy = r / 3 - 1, dz = r % 3 - 1;
        int nx = c.y + dx, ny = c.z + dy, nz = c.w + dz;
        if ((unsigned)nx < S && (unsigned)ny < S && (unsigned)nz < S) {
            j = tab_lookup(tab, kb + dx * (S * S) + dy * S + dz);
            if (j >= 0) hit = scores[j] > TAU;
        }
    }
    u64 hm = __ballot(hit);
    int c27 = __popcll(hm);
    float fsum = 0.f;
    u64 m = hm;
    while (m) {
        int src = __ffsll((long long)m) - 1;
        m &= m - 1;
        int jj = __shfl(j, src);
        fsum += feats[(size_t)jj * 64 + lane];
    }
    float favg = fsum / fmaxf((float)c27, 1.0f);
    int d = lane & 31;
    float acc = bias[d];
    #pragma unroll
    for (int l = 0; l < 64; l++) {
        float fl = __shfl(favg, l);
        acc = fmaf(fl, W[l * 32 + d], acc);
    }
    float ss = acc * acc;
    #pragma unroll
    for (int off = 1; off < 32; off <<= 1) ss += __shfl_xor(ss, off);
    float inv = 1.0f / fmaxf(sqrtf(ss), 1e-12f);
    if (lane < 32) row[lane] = acc * inv;
}

extern "C" void kernel_launch(void* const* d_in, const int* in_sizes, int n_in,
                              void* d_out, int out_size, void* d_ws, size_t ws_size,
                              hipStream_t stream) {
    const int* coords = (const int*)d_in[0];
    const float* feats = (const float*)d_in[1];
    const float* scores = (const float*)d_in[2];
    const float* W = (const float*)d_in[3];
    const float* bias = (const float*)d_in[4];
    const float* background = (const float*)d_in[5];
    int N = in_sizes[0] / 4;
    float* out = (float*)d_out;
    int pcap = N / 2;

    char* ws = (char*)d_ws;
    size_t off = 0;
    u64* tab = (u64*)(ws + off); off += (size_t)TAB_SZ * 8;
    // zero-region start: bm, hist, cnt, ccnt, thrbin contiguous
    size_t zoff = off;
    u32* bm = (u32*)(ws + off); off += (size_t)BM_WORDS * 4;
    int* hist = (int*)(ws + off); off += (size_t)NB * NBINS * 4;
    int* cnt = (int*)(ws + off); off += (size_t)NB * CPAD * 4;
    int* ccnt = (int*)(ws + off); off += (size_t)NB * CPAD * 4;
    u32* thrbin = (u32*)(ws + off); off += 256;
    size_t zlen = off - zoff;
    u64* peaks = (u64*)(ws + off); off += (size_t)NB * pcap * 8;
    u64* cand = (u64*)(ws + off); off += (size_t)NB * CAND_CAP * 8;
    u64* bufA = (u64*)(ws + off); off += (size_t)NB * CAND_CAP * 8;
    u64* selected = (u64*)(ws + off); off += (size_t)NB * KSEL * 8;

    hipMemsetAsync(tab, 0xFF, (size_t)TAB_SZ * 8, stream);   // EMPTY64
    hipMemsetAsync(ws + zoff, 0, zlen, stream);              // bm/hist/cnt/ccnt/thrbin
    k_insert<<<(N + 255) / 256, 256, 0, stream>>>(coords, scores, tab, bm, N);
    k_peak<<<(N + 255) / 256, 256, 0, stream>>>(coords, scores, tab, bm,
                                                peaks, cnt, hist, N, pcap);
    k_desc<<<(N + 255) / 256, 256, 0, stream>>>(feats, W, bias, out + NB * KSEL, N);
    k_thresh<<<1, 256, 0, stream>>>(hist, cnt, thrbin, pcap);
    k_compact<<<(NB * pcap + 255) / 256, 256, 0, stream>>>(peaks, cnt, thrbin, cand, ccnt, pcap);
    k_topk<<<NB, 256, 0, stream>>>(cand, ccnt, bufA, selected);
    k_final<<<(NB * KSEL + NB + 3) / 4, 256, 0, stream>>>(coords, feats, scores, W, bias,
                                                          background, tab, selected, out, N);
}

// Round 10
// 281.103 us; speedup vs baseline: 1.3134x; 1.2721x over previous
//
#include <hip/hip_runtime.h>
#include <math.h>

#define S 256
#define NB 4
#define TAU 0.1f
#define KSEL 128
#define LOG_TAB 21
#define TAB_SZ (1u << LOG_TAB)
#define TAB_MASK (TAB_SZ - 1)
#define EMPTY64 0xFFFFFFFFFFFFFFFFull
#define BM_WORDS (1u << 21)   // 4*256^3 bits / 32
#define NBINS 8192
#define BIN_BASE 0x3D800      // (0x3D800000 >> 12), conf floor 0.0625 < TAU
#define CAND_CAP 4096
#define CPAD 32               // ints per counter slot -> one 128B line each

typedef unsigned long long u64;
typedef unsigned int u32;

__device__ __forceinline__ u32 hash_key(int key) {
    u32 h = (u32)key * 0x9E3779B1u;
    h ^= h >> 15;
    return h & TAB_MASK;
}

__device__ __forceinline__ int conf_bin(float conf) {
    int bin = (int)(__float_as_uint(conf) >> 12) - BIN_BASE;
    return bin < 0 ? 0 : (bin > NBINS - 1 ? NBINS - 1 : bin);
}

__device__ __forceinline__ int tab_lookup(const u64* __restrict__ tab, int key) {
    u32 slot = hash_key(key);
    for (;;) {
        u64 e = tab[slot];
        if ((u32)(e >> 32) == (u32)key) return (int)(u32)e;
        if (e == EMPTY64) return -1;
        slot = (slot + 1) & TAB_MASK;
    }
}

// ---- desc row body: register staging + issue fence + uniform-W GEMV ----
__device__ __forceinline__ void desc_row(const float* __restrict__ feats,
                                         const float* __restrict__ W,
                                         const float* __restrict__ bias,
                                         float* __restrict__ voxel_desc, int i, int N) {
    if (i >= N) return;
    const float4* row4 = (const float4*)(feats + (size_t)i * 64);
    float4 r[16];
    #pragma unroll
    for (int k = 0; k < 16; k++) r[k] = row4[k];
    asm volatile("" ::: "memory");   // loads cannot sink past this: 16 in flight
    float acc[32];
    #pragma unroll
    for (int d = 0; d < 32; d++) acc[d] = bias[d];
    #pragma unroll
    for (int k = 0; k < 16; k++) {
        float4 f = r[k];
        const float* Wb = W + k * 4 * 32;   // thread-uniform -> scalar loads
        #pragma unroll
        for (int d = 0; d < 32; d++) {
            acc[d] = fmaf(f.x, Wb[d], acc[d]);
            acc[d] = fmaf(f.y, Wb[32 + d], acc[d]);
            acc[d] = fmaf(f.z, Wb[64 + d], acc[d]);
            acc[d] = fmaf(f.w, Wb[96 + d], acc[d]);
        }
    }
    float ss = 0.f;
    #pragma unroll
    for (int d = 0; d < 32; d++) ss += acc[d] * acc[d];
    float inv = 1.0f / fmaxf(sqrtf(ss), 1e-12f);
    float4* out4 = (float4*)(voxel_desc + (size_t)i * 32);
    #pragma unroll
    for (int q = 0; q < 8; q++) {
        float4 o;
        o.x = acc[q * 4 + 0] * inv; o.y = acc[q * 4 + 1] * inv;
        o.z = acc[q * 4 + 2] * inv; o.w = acc[q * 4 + 3] * inv;
        out4[q] = o;
    }
}

// ---- insert body ----
__device__ __forceinline__ void insert_pt(const int* __restrict__ coords,
                                          const float* __restrict__ scores,
                                          u64* __restrict__ tab, u32* __restrict__ bm,
                                          int i, int N) {
    if (i >= N) return;
    int4 c = ((const int4*)coords)[i];
    float conf = scores[i];
    int key = ((c.x * S + c.y) * S + c.z) * S + c.w;
    if (conf > TAU) atomicOr(&bm[(u32)key >> 5], 1u << (key & 31));
    u64 ins = ((u64)(u32)key << 32) | (u32)i;
    u32 slot = hash_key(key);
    for (;;) {
        u64 e = tab[slot];
        if ((u32)(e >> 32) == (u32)key) { atomicMin(&tab[slot], ins); return; }
        if (e == EMPTY64) {
            u64 prev = atomicCAS(&tab[slot], EMPTY64, ins);
            if (prev == EMPTY64) return;
            if ((u32)(prev >> 32) == (u32)key) { atomicMin(&tab[slot], ins); return; }
        }
        slot = (slot + 1) & TAB_MASK;
    }
}

// Fused: role-interleaved insert (2 of 3 blocks) + desc first-half (1 of 3).
__global__ __launch_bounds__(256, 4) void k_ins_desc(const int* __restrict__ coords,
        const float* __restrict__ scores, u64* __restrict__ tab, u32* __restrict__ bm,
        const float* __restrict__ feats, const float* __restrict__ W,
        const float* __restrict__ bias, float* __restrict__ voxel_desc,
        int N, int nIns, int nDesc, int descRow0) {
    int g = blockIdx.x / 3, r = blockIdx.x % 3;
    if (r < 2) {
        int ib = g * 2 + r;
        if (ib >= nIns) return;
        insert_pt(coords, scores, tab, bm, ib * 256 + threadIdx.x, N);
    } else {
        if (g >= nDesc) return;
        desc_row(feats, W, bias, voxel_desc, descRow0 + g * 256 + threadIdx.x, N);
    }
}

// ---- peak body (whole block executes this role) ----
__device__ __forceinline__ void peak_block(const int* __restrict__ coords,
        const float* __restrict__ scores, const u64* __restrict__ tab,
        const u32* __restrict__ bm, u64* __restrict__ peaks, int* __restrict__ cnt,
        int* __restrict__ hist, int N, int pcap, int pb) {
    int i = pb * 256 + threadIdx.x;
    bool alive = (i < N);
    int ii = alive ? i : 0;
    int4 c = ((const int4*)coords)[ii];
    float conf = alive ? scores[ii] : -1.0f;
    int kb = ((c.x * S + c.y) * S + c.z) * S + c.w;
    bool ispeak = false;
    if (alive && conf > TAU) {
        u32 m27 = 0;
        u32 vzm = (u32)((c.w > 0) ? 1 : 0) | 2u | (u32)((c.w < S - 1) ? 4 : 0);
        #pragma unroll
        for (int dx = -1; dx <= 1; dx++) {
            if ((unsigned)(c.y + dx) >= S) continue;
            #pragma unroll
            for (int dy = -1; dy <= 1; dy++) {
                if ((unsigned)(c.z + dy) >= S) continue;
                int nk = kb + dx * (S * S) + dy * S;
                u32 idx = (u32)nk >> 5;
                int sft = nk & 31;
                u32 w0 = bm[idx];
                u32 b3;
                if (sft >= 1 && sft <= 30) {
                    b3 = (w0 >> (sft - 1)) & 7u;
                } else if (sft == 0) {
                    u32 wm = (nk >= 32) ? bm[idx - 1] : 0u;
                    b3 = ((wm >> 31) & 1u) | ((w0 & 3u) << 1);
                } else {
                    u32 wp = (idx + 1 < BM_WORDS) ? bm[idx + 1] : 0u;
                    b3 = ((w0 >> 30) & 3u) | ((wp & 1u) << 2);
                }
                b3 &= vzm;
                int p = ((dx + 1) * 3 + (dy + 1)) * 3;
                m27 |= b3 << p;
            }
        }
        float hmax = -INFINITY;
        while (m27) {
            int q = __builtin_ctz(m27);
            m27 &= m27 - 1;
            int dx = q / 9 - 1;
            int rr = q % 9;
            int dy = rr / 3 - 1, dz = rr % 3 - 1;
            int j = tab_lookup(tab, kb + dx * (S * S) + dy * S + dz);
            if (j >= 0) hmax = fmaxf(hmax, scores[j]);
        }
        ispeak = (hmax == conf);
    }

    if (ispeak) atomicAdd(&hist[c.x * NBINS + conf_bin(conf)], 1);

    __shared__ int wcnt[4][NB];
    __shared__ int bbase[NB];
    int w = threadIdx.x >> 6;
    int lane = threadIdx.x & 63;
    u64 lmask_lt = (lane == 63) ? 0x7FFFFFFFFFFFFFFFull : ((1ull << lane) - 1ull);
    u64 mb[NB];
    #pragma unroll
    for (int b = 0; b < NB; b++) {
        mb[b] = __ballot(ispeak && (c.x == b));
        if (lane == 0) wcnt[w][b] = __popcll(mb[b]);
    }
    __syncthreads();
    if (threadIdx.x < NB) {
        int b = threadIdx.x;
        int tot = wcnt[0][b] + wcnt[1][b] + wcnt[2][b] + wcnt[3][b];
        bbase[b] = tot > 0 ? atomicAdd(&cnt[b * CPAD], tot) : 0;
    }
    __syncthreads();
    if (ispeak) {
        int b = c.x;
        int pre = 0;
        for (int w2 = 0; w2 < w; w2++) pre += wcnt[w2][b];
        int rank = __popcll(mb[b] & lmask_lt);
        int pidx = bbase[b] + pre + rank;
        if (pidx < pcap)
            peaks[(size_t)b * pcap + pidx] =
                ((u64)__float_as_uint(conf) << 32) | (u32)(~(u32)i);
    }
}

// Fused: role-interleaved peak (2 of 3 blocks) + desc second-half (1 of 3).
__global__ __launch_bounds__(256, 4) void k_peak_desc(const int* __restrict__ coords,
        const float* __restrict__ scores, const u64* __restrict__ tab,
        const u32* __restrict__ bm, u64* __restrict__ peaks, int* __restrict__ cnt,
        int* __restrict__ hist, const float* __restrict__ feats,
        const float* __restrict__ W, const float* __restrict__ bias,
        float* __restrict__ voxel_desc, int N, int pcap,
        int nPeak, int nDesc, int descRow0) {
    int g = blockIdx.x / 3, r = blockIdx.x % 3;
    if (r < 2) {
        int pb = g * 2 + r;
        if (pb >= nPeak) return;
        peak_block(coords, scores, tab, bm, peaks, cnt, hist, N, pcap, pb);
    } else {
        if (g >= nDesc) return;
        desc_row(feats, W, bias, voxel_desc, descRow0 + g * 256 + threadIdx.x, N);
    }
}

// One block; wave b finds per-batch threshold bin (count of bins >= thr covers K).
__global__ void k_thresh(const int* __restrict__ hist, const int* __restrict__ cnt,
                         u32* __restrict__ thrbin, int pcap) {
    int w = threadIdx.x >> 6;
    int lane = threadIdx.x & 63;
    if (w >= NB) return;
    int n = cnt[w * CPAD]; if (n > pcap) n = pcap;
    int need = n < KSEL ? n : KSEL;
    const int* h = hist + w * NBINS;
    int running = 0;
    u32 thr = 0;
    for (int hi = NBINS - 64; hi >= 0; hi -= 64) {
        int v = h[hi + lane];
        int s = v;
        #pragma unroll
        for (int off = 1; off < 64; off <<= 1) {
            int o = __shfl_down(s, off);
            if (lane + off < 64) s += o;
        }
        int csum = __shfl(s, 0);
        if (running + csum >= need) {
            u64 m = __ballot(running + s >= need);
            int top = 63 - __builtin_clzll(m);
            thr = (u32)(hi + top);
            break;
        }
        running += csum;
    }
    if (lane == 0) thrbin[w] = thr;
}

__global__ void k_compact(const u64* __restrict__ peaks, const int* __restrict__ cnt,
                          const u32* __restrict__ thrbin, u64* __restrict__ cand,
                          int* __restrict__ ccnt, int pcap) {
    int t = blockIdx.x * blockDim.x + threadIdx.x;
    int b = t / pcap;
    if (b >= NB) return;
    int e = t % pcap;
    int n = cnt[b * CPAD]; if (n > pcap) n = pcap;
    if (e >= n) return;
    u64 key = peaks[(size_t)b * pcap + e];
    float conf = __uint_as_float((u32)(key >> 32));
    if (conf_bin(conf) >= (int)thrbin[b]) {
        int p = atomicAdd(&ccnt[b * CPAD], 1);
        if (p < CAND_CAP) cand[(size_t)b * CAND_CAP + p] = key;
    }
}

// Per-batch exact top-K over the small candidate set (radix select + bitonic sort).
__global__ void k_topk(u64* __restrict__ cand, const int* __restrict__ ccnt,
                       u64* __restrict__ bufA, u64* __restrict__ selected) {
    int b = blockIdx.x;
    int tid = threadIdx.x;
    __shared__ int hist[256];
    __shared__ int sh_split, sh_above, sh_selc, sh_candc;
    u64* sel = selected + b * KSEL;
    u64* pcur = cand + (size_t)b * CAND_CAP;
    u64* pnxt = bufA + (size_t)b * CAND_CAP;
    int n = ccnt[b * CPAD];
    if (n > CAND_CAP) n = CAND_CAP;
    int need = KSEL, nsel = 0;

    for (int byte = 7; byte >= 0; byte--) {
        if (need <= 0) break;
        if (n <= need) {
            for (int idx = tid; idx < n; idx += blockDim.x) sel[nsel + idx] = pcur[idx];
            nsel += n; need -= n; n = 0;
            break;
        }
        hist[tid] = 0;
        __syncthreads();
        int shift = byte * 8;
        for (int idx = tid; idx < n; idx += blockDim.x)
            atomicAdd(&hist[(int)((pcur[idx] >> shift) & 255)], 1);
        __syncthreads();
        if (tid == 0) {
            int above = 0, s = 255;
            for (; s > 0; s--) {
                if (above + hist[s] >= need) break;
                above += hist[s];
            }
            sh_split = s; sh_above = above; sh_selc = 0; sh_candc = 0;
        }
        __syncthreads();
        int s = sh_split;
        for (int idx = tid; idx < n; idx += blockDim.x) {
            u64 e = pcur[idx];
            int bv = (int)((e >> shift) & 255);
            if (bv > s) { int p = atomicAdd(&sh_selc, 1); sel[nsel + p] = e; }
            else if (bv == s) { int p = atomicAdd(&sh_candc, 1); pnxt[p] = e; }
        }
        __syncthreads();
        nsel += sh_above; need -= sh_above; n = sh_candc;
        u64* t = pcur; pcur = pnxt; pnxt = t;
        __syncthreads();
    }
    if (need > 0 && n > 0) {
        int take = need < n ? need : n;
        for (int idx = tid; idx < take; idx += blockDim.x) sel[nsel + idx] = pcur[idx];
        nsel += take;
    }
    for (int idx = nsel + tid; idx < KSEL; idx += blockDim.x) sel[idx] = 0;
    __syncthreads();

    __shared__ u64 sk[KSEL];
    if (tid < KSEL) sk[tid] = sel[tid];
    __syncthreads();
    for (int k = 2; k <= KSEL; k <<= 1) {
        for (int j = k >> 1; j > 0; j >>= 1) {
            if (tid < KSEL) {
                int ixj = tid ^ j;
                if (ixj > tid) {
                    u64 a = sk[tid], c2 = sk[ixj];
                    bool upper = (tid & k) != 0;
                    if (upper ? (a > c2) : (a < c2)) { sk[tid] = c2; sk[ixj] = a; }
                }
            }
            __syncthreads();
        }
    }
    if (tid < KSEL) sel[tid] = sk[tid];
}

// Wave-per-peak finalize: parallel probes, coalesced feats gather, shfl GEMV.
__global__ void k_final(const int* __restrict__ coords, const float* __restrict__ feats,
                        const float* __restrict__ scores, const float* __restrict__ W,
                        const float* __restrict__ bias, const float* __restrict__ background,
                        const u64* __restrict__ tab, const u64* __restrict__ selected,
                        float* __restrict__ out, int N) {
    int gw = (blockIdx.x * blockDim.x + threadIdx.x) >> 6;
    int lane = threadIdx.x & 63;
    float* full = out + NB * KSEL + (size_t)N * 32;
    if (gw >= NB * KSEL) {
        int b = gw - NB * KSEL;
        if (b < NB && lane < 32)
            full[(size_t)(b * (KSEL + 1)) * 32 + lane] = background[lane];
        return;
    }
    int b = gw >> 7, k = gw & 127;
    u64 key = selected[gw];
    float* row = full + (size_t)(b * (KSEL + 1) + 1 + k) * 32;
    if (key == 0ull) {
        if (lane == 0) out[gw] = 0.f;
        if (lane < 32) row[lane] = 0.f;
        return;
    }
    float conf = __uint_as_float((u32)(key >> 32));
    int i = (int)(~(u32)key);
    if (lane == 0) out[gw] = conf;
    int4 c = ((const int4*)coords)[i];
    int kb = ((c.x * S + c.y) * S + c.z) * S + c.w;
    int j = -1; bool hit = false;
    if (lane < 27) {
        int dx = lane / 9 - 1, r = lane % 9;
        int dy = r / 3 - 1, dz = r % 3 - 1;
        int nx = c.y + dx, ny = c.z + dy, nz = c.w + dz;
        if ((unsigned)nx < S && (unsigned)ny < S && (unsigned)nz < S) {
            j = tab_lookup(tab, kb + dx * (S * S) + dy * S + dz);
            if (j >= 0) hit = scores[j] > TAU;
        }
    }
    u64 hm = __ballot(hit);
    int c27 = __popcll(hm);
    float fsum = 0.f;
    u64 m = hm;
    while (m) {
        int src = __ffsll((long long)m) - 1;
        m &= m - 1;
        int jj = __shfl(j, src);
        fsum += feats[(size_t)jj * 64 + lane];
    }
    float favg = fsum / fmaxf((float)c27, 1.0f);
    int d = lane & 31;
    float acc = bias[d];
    #pragma unroll
    for (int l = 0; l < 64; l++) {
        float fl = __shfl(favg, l);
        acc = fmaf(fl, W[l * 32 + d], acc);
    }
    float ss = acc * acc;
    #pragma unroll
    for (int off = 1; off < 32; off <<= 1) ss += __shfl_xor(ss, off);
    float inv = 1.0f / fmaxf(sqrtf(ss), 1e-12f);
    if (lane < 32) row[lane] = acc * inv;
}

extern "C" void kernel_launch(void* const* d_in, const int* in_sizes, int n_in,
                              void* d_out, int out_size, void* d_ws, size_t ws_size,
                              hipStream_t stream) {
    const int* coords = (const int*)d_in[0];
    const float* feats = (const float*)d_in[1];
    const float* scores = (const float*)d_in[2];
    const float* W = (const float*)d_in[3];
    const float* bias = (const float*)d_in[4];
    const float* background = (const float*)d_in[5];
    int N = in_sizes[0] / 4;
    float* out = (float*)d_out;
    int pcap = N / 2;

    char* ws = (char*)d_ws;
    size_t off = 0;
    u64* tab = (u64*)(ws + off); off += (size_t)TAB_SZ * 8;
    size_t zoff = off;
    u32* bm = (u32*)(ws + off); off += (size_t)BM_WORDS * 4;
    int* hist = (int*)(ws + off); off += (size_t)NB * NBINS * 4;
    int* cnt = (int*)(ws + off); off += (size_t)NB * CPAD * 4;
    int* ccnt = (int*)(ws + off); off += (size_t)NB * CPAD * 4;
    u32* thrbin = (u32*)(ws + off); off += 256;
    size_t zlen = off - zoff;
    u64* peaks = (u64*)(ws + off); off += (size_t)NB * pcap * 8;
    u64* cand = (u64*)(ws + off); off += (size_t)NB * CAND_CAP * 8;
    u64* bufA = (u64*)(ws + off); off += (size_t)NB * CAND_CAP * 8;
    u64* selected = (u64*)(ws + off); off += (size_t)NB * KSEL * 8;

    int nBlk = (N + 255) / 256;            // 3125 insert/peak blocks
    int nDescA = nBlk / 2;                 // 1562 desc blocks in fused1
    int rowsA = nDescA * 256;
    int nDescB = (N - rowsA + 255) / 256;  // 1563 desc blocks in fused2
    int grid1 = 3 * ((nBlk + 1) / 2 > nDescA ? (nBlk + 1) / 2 : nDescA);
    int grid2 = 3 * ((nBlk + 1) / 2 > nDescB ? (nBlk + 1) / 2 : nDescB);

    hipMemsetAsync(tab, 0xFF, (size_t)TAB_SZ * 8, stream);   // EMPTY64
    hipMemsetAsync(ws + zoff, 0, zlen, stream);              // bm/hist/cnt/ccnt/thrbin
    k_ins_desc<<<grid1, 256, 0, stream>>>(coords, scores, tab, bm,
                                          feats, W, bias, out + NB * KSEL,
                                          N, nBlk, nDescA, 0);
    k_peak_desc<<<grid2, 256, 0, stream>>>(coords, scores, tab, bm, peaks, cnt, hist,
                                           feats, W, bias, out + NB * KSEL,
                                           N, pcap, nBlk, nDescB, rowsA);
    k_thresh<<<1, 256, 0, stream>>>(hist, cnt, thrbin, pcap);
    k_compact<<<(NB * pcap + 255) / 256, 256, 0, stream>>>(peaks, cnt, thrbin, cand, ccnt, pcap);
    k_topk<<<NB, 256, 0, stream>>>(cand, ccnt, bufA, selected);
    k_final<<<(NB * KSEL + NB + 3) / 4, 256, 0, stream>>>(coords, feats, scores, W, bias,
                                                          background, tab, selected, out, N);
}